// Round 13
// baseline (955.752 us; speedup 1.0000x reference)
//
#include <hip/hip_runtime.h>

// SP_DNN: two fused 1->256->256->256->256 MLPs (sin activations) + strided rowwise dot.
// fp16 MFMA, fp32 accumulate.
//
// R13 = R12 with the prepack bit-decode typo fixed: gg = (r>>13)&7, was
// (r>>14)&7 (field map j:0-2, l:3-8, ks:9, ci:10, wv:11-12, gg:13-15;
// idx = gg*8192+wv*2048+ci*1024+ks*512+l*8+j == r only with >>13). R12's
// failure was wrong weights in half the K-groups, NOT the fragment layout.
//
// Structure (R12): 32x32x16 MFMA (measured 2382 vs 2075 TF, half the issue
// slots); hswz32 swizzle (unit ^= m&31) -> B-reads at the 8-clock b128
// structural floor, wb f16x4 stores conflict-free; A and B both depth-2
// pipelined; 6 alternating x/t GEMM phases with writeback + layer0_t sliced
// into the MFMA shadow; lgkm-only raw barriers; params in LDS; 2 blk/CU.
// Fragment layouts (generalization HW-validated by the 16x16x32 kernel):
// A/B: M(N)=lane&31, k=(lane>>5)*8+j; D: col=lane&31=batch row,
// row=(reg&3)+8*(reg>>2)+4*(lane>>5).

typedef _Float16 f16x8 __attribute__((ext_vector_type(8)));
typedef _Float16 f16x4 __attribute__((ext_vector_type(4)));
typedef float f32x4 __attribute__((ext_vector_type(4)));
typedef float f32x16 __attribute__((ext_vector_type(16)));

// Swizzled act-buffer byte offset: row m (0..63, 512 B stride), kbyte in
// [0,512). 16B-unit index XORed with (m&31): a 32-row column slice (the
// 32x32 B-read) covers 32 distinct units -> all banks, 2 lanes/unit (free);
// wb f16x4 stores: lane pairs (l, l+32) share a unit at the same row in
// disjoint 8B halves -> zero conflict.
__device__ __forceinline__ int hswz32(int m, int kbyte) {
    return m * 512 + ((((kbyte >> 4) ^ m) & 31) << 4) + (kbyte & 15);
}

// Raw workgroup barrier draining LDS ops only; global loads stay in flight.
__device__ __forceinline__ void barrier_lds() {
    asm volatile("s_waitcnt lgkmcnt(0)" ::: "memory");
    __builtin_amdgcn_s_barrier();
}

// ---------------------------------------------------------------------------
// Prepack: 6 matrices W[k][n] (256x256 f32, k-major) -> fp16 A-fragment-major
// for 32x32x16: within a layer,
//   idx = gg*8192 + wv*2048 + (ci*2+ks)*512 + l*8 + j
//   n = wv*64 + ci*32 + (l&31),  k = gg*32 + ks*16 + (l>>5)*8 + j
// ---------------------------------------------------------------------------
__global__ void prepack(const float* __restrict__ xW1, const float* __restrict__ xW2,
                        const float* __restrict__ xW3, const float* __restrict__ tW1,
                        const float* __restrict__ tW2, const float* __restrict__ tW3,
                        _Float16* __restrict__ dst)
{
    int g = blockIdx.x * 256 + threadIdx.x;   // 6*65536 threads exactly
    int L = g >> 16;
    int r = g & 65535;
    int j  = r & 7;            // bits 0-2
    int l  = (r >> 3) & 63;    // bits 3-8
    int ks = (r >> 9) & 1;     // bit 9
    int ci = (r >> 10) & 1;    // bit 10
    int wv = (r >> 11) & 3;    // bits 11-12
    int gg = (r >> 13) & 7;    // bits 13-15  (R12 bug: was >>14)
    const float* W;
    switch (L) {
        case 0: W = xW1; break;
        case 1: W = xW2; break;
        case 2: W = xW3; break;
        case 3: W = tW1; break;
        case 4: W = tW2; break;
        default: W = tW3; break;
    }
    int n = wv * 64 + ci * 32 + (l & 31);
    int k = gg * 32 + ks * 16 + ((l >> 5) & 1) * 8 + j;
    dst[g] = (_Float16)W[k * 256 + n];
}

// ---------------------------------------------------------------------------
// Main fused kernel. Block = 256 threads (4 waves), tile = 64 rows.
// Wave w owns out-channels [w*64, w*64+64) in every 256->256 layer.
// Per wave: acc[ci][ri] = 2x2 tiles of 32ch x 32rows (f32x16 each).
// ---------------------------------------------------------------------------

__device__ __forceinline__ void layer0_scalar(
    float xv, const float* __restrict__ W0, const float* __restrict__ b0,
    _Float16* __restrict__ hb, int tid)
{
    int m = tid >> 2;        // 64 rows, 4 threads per row
    int q = tid & 3;
#pragma unroll
    for (int g = 0; g < 8; ++g) {
        int n0 = g * 32 + q * 8;        // 4 q-addresses -> 4 distinct banks
        f16x8 hv;
#pragma unroll
        for (int e = 0; e < 8; ++e) {
            float z = fmaf(xv, W0[n0 + e], b0[n0 + e]);
            hv[e] = (_Float16)__sinf(z);
        }
        *(f16x8*)((char*)hb + hswz32(m, n0 * 2)) = hv;
    }
}

// One GEMM phase: acc = Wl x rb (8 K-groups of K=32, 8 MFMAs of 32x32x16 each).
// A: afr[2][4] depth-2 register pipeline; frag f = ci*2+ks. Refill buf[g&1]
//    for g+2 after last use; g=6/7 load Wnext's g0/g1 (in flight across bar).
// B: bfr[2][4] depth-2 LDS pipeline; frag f = ri*2+ks. Same parity scheme.
// MODE 1: slice the OTHER MLP's writeback sin(wacc+bias[LDS]) -> wb_lds,
//         2 f16x4 stores per g (store s=2g+jo: ci=s>>3, ri=(s>>2)&1, gq=s&3).
// MODE 2: slice layer0_t, one 8-channel group per g.
template<int MODE>   // 0 plain, 1 writeback, 2 layer0-slice
__device__ __forceinline__ void gemm_phase(
    const _Float16* __restrict__ Wl,
    const _Float16* __restrict__ Wnext,    // nullptr at the end
    const _Float16* __restrict__ rb,       // LDS read buffer (activations)
    f32x16 acc[2][2], f16x8 afr[2][4],
    f32x16 wacc[2][2],                     // MODE 1: prev phase's acc
    const float* __restrict__ wbias,       // MODE 1: LDS bias for wacc
    _Float16* __restrict__ wb_lds,         // MODE 1/2: LDS write target
    float xv,                              // MODE 2: scalar input
    const float* __restrict__ W0,          // MODE 2: LDS 1->256 weights
    const float* __restrict__ b0,          // MODE 2: LDS bias
    int tid, int lane, int wave)
{
    const int ml = lane & 31;              // M/N index within 32-tile
    const int kh = lane >> 5;              // k-half select

    f32x16 zero;
#pragma unroll
    for (int e = 0; e < 16; ++e) zero[e] = 0.f;
#pragma unroll
    for (int ci = 0; ci < 2; ++ci)
#pragma unroll
        for (int ri = 0; ri < 2; ++ri)
            acc[ci][ri] = zero;

    const _Float16* abase = Wl + wave * 2048 + lane * 8;

    // B prologue: g0 -> buf0, g1 -> buf1 (8 ds_read_b128).
    f16x8 bfr[2][4];
#pragma unroll
    for (int s = 0; s < 2; ++s)
#pragma unroll
        for (int ri = 0; ri < 2; ++ri)
#pragma unroll
            for (int ks = 0; ks < 2; ++ks)
                bfr[s][ri * 2 + ks] = *(const f16x8*)((const char*)rb +
                    hswz32(ri * 32 + ml, s * 64 + ks * 32 + kh * 16));

#pragma unroll
    for (int g = 0; g < 8; ++g) {
        __builtin_amdgcn_s_setprio(1);
#pragma unroll
        for (int ks = 0; ks < 2; ++ks)
#pragma unroll
            for (int ci = 0; ci < 2; ++ci)
#pragma unroll
                for (int ri = 0; ri < 2; ++ri)
                    acc[ci][ri] = __builtin_amdgcn_mfma_f32_32x32x16_f16(
                        afr[g & 1][ci * 2 + ks], bfr[g & 1][ri * 2 + ks],
                        acc[ci][ri], 0, 0, 0);
        __builtin_amdgcn_s_setprio(0);

        // B refill buf[g&1] for g+2 (program-order after its last MFMA use).
        if (g < 6) {
#pragma unroll
            for (int ri = 0; ri < 2; ++ri)
#pragma unroll
                for (int ks = 0; ks < 2; ++ks)
                    bfr[g & 1][ri * 2 + ks] = *(const f16x8*)((const char*)rb +
                        hswz32(ri * 32 + ml, (g + 2) * 64 + ks * 32 + kh * 16));
        }
        // A refill buf[g&1] for g+2; g=6/7 chain to the NEXT phase's g0/g1.
        if (g < 6) {
#pragma unroll
            for (int f = 0; f < 4; ++f)
                afr[g & 1][f] = *(const f16x8*)(abase + (g + 2) * 8192 + f * 512);
        } else if (Wnext) {
#pragma unroll
            for (int f = 0; f < 4; ++f)
                afr[g & 1][f] = *(const f16x8*)(Wnext + (g - 6) * 8192 +
                                                wave * 2048 + lane * 8 + f * 512);
        }

        if (MODE == 1) {                 // writeback slice: 2 f16x4 stores
#pragma unroll
            for (int jo = 0; jo < 2; ++jo) {
                const int s  = g * 2 + jo;
                const int ci = s >> 3, ri = (s >> 2) & 1, gq = s & 3;
                const int nb = wave * 64 + ci * 32 + gq * 8 + 4 * kh;
                f32x4 bv = *(const f32x4*)&wbias[nb];
                f16x4 hv;
                hv[0] = (_Float16)__sinf(wacc[ci][ri][gq * 4 + 0] + bv[0]);
                hv[1] = (_Float16)__sinf(wacc[ci][ri][gq * 4 + 1] + bv[1]);
                hv[2] = (_Float16)__sinf(wacc[ci][ri][gq * 4 + 2] + bv[2]);
                hv[3] = (_Float16)__sinf(wacc[ci][ri][gq * 4 + 3] + bv[3]);
                *(f16x4*)((char*)wb_lds + hswz32(ri * 32 + ml, nb * 2)) = hv;
            }
        } else if (MODE == 2) {          // layer0 slice: one 8-ch group
            const int m = tid >> 2, q = tid & 3;
            const int n0 = g * 32 + q * 8;
            f16x8 hv;
#pragma unroll
            for (int e = 0; e < 8; ++e) {
                float z = fmaf(xv, W0[n0 + e], b0[n0 + e]);
                hv[e] = (_Float16)__sinf(z);
            }
            *(f16x8*)((char*)wb_lds + hswz32(m, n0 * 2)) = hv;
        }
    }
}

__global__ __launch_bounds__(256, 2)
void mlp_fused(const float* __restrict__ x,
               const float* __restrict__ xW0, const float* __restrict__ xb0,
               const float* __restrict__ xb1, const float* __restrict__ xb2,
               const float* __restrict__ xb3,
               const float* __restrict__ tW0, const float* __restrict__ tb0,
               const float* __restrict__ tb1, const float* __restrict__ tb2,
               const float* __restrict__ tb3,
               const _Float16* __restrict__ Wp,
               float* __restrict__ out)
{
    __shared__ __align__(16) _Float16 hbuf[2][64 * 256];   // [0]=x acts, [1]=t acts
    __shared__ __align__(16) float    params[10 * 256];    // 10 KB small params

    const int tid = threadIdx.x;
    const int lane = tid & 63;
    const int wave = tid >> 6;       // 0..3
    const int ml = lane & 31;
    const int kh = lane >> 5;
    const int row0 = blockIdx.x * 64;

    // Preload all small params to LDS.
    // segs: 0 xW0, 1 xb0, 2 tW0, 3 tb0, 4 xb1, 5 xb2, 6 xb3, 7 tb1, 8 tb2, 9 tb3
    {
        const float* psrc[10] = {xW0, xb0, tW0, tb0, xb1, xb2, xb3, tb1, tb2, tb3};
#pragma unroll
        for (int s = 0; s < 10; ++s)
            params[s * 256 + tid] = psrc[s][tid];
    }
    const float2 xv2 = ((const float2*)x)[row0 + (tid >> 2)];  // both MLP inputs

    f32x16 xacc[2][2], tacc[2][2];   // 128 AGPR
    f16x8 afr[2][4];                 // A-fragment register double-buffer (32 VGPR)

    // Prologue: xW1 g0 -> buf0, g1 -> buf1; land during layer0_x's sin work.
#pragma unroll
    for (int s = 0; s < 2; ++s)
#pragma unroll
        for (int f = 0; f < 4; ++f)
            afr[s][f] = *(const f16x8*)(Wp + s * 8192 + wave * 2048 +
                                        lane * 8 + f * 512);
    barrier_lds();                    // params visible to all waves

    // ----- layer0_x -----
    layer0_scalar(xv2.x, &params[0], &params[256], hbuf[0], tid);
    barrier_lds();                    // x acts visible

    // ----- 6 alternating GEMM phases -----
    // P1: x1; layer0_t sliced in -> hbuf[1]
    gemm_phase<2>(Wp + 0 * 65536, Wp + 3 * 65536, hbuf[0], xacc, afr,
                  nullptr, nullptr, hbuf[1],
                  xv2.y, &params[2 * 256], &params[3 * 256], tid, lane, wave);
    barrier_lds();
    // P2: t1 || wb_x1 -> hbuf[0]
    gemm_phase<1>(Wp + 3 * 65536, Wp + 1 * 65536, hbuf[1], tacc, afr,
                  xacc, &params[4 * 256], hbuf[0],
                  0.f, nullptr, nullptr, tid, lane, wave);
    barrier_lds();
    // P3: x2 || wb_t1 -> hbuf[1]
    gemm_phase<1>(Wp + 1 * 65536, Wp + 4 * 65536, hbuf[0], xacc, afr,
                  tacc, &params[7 * 256], hbuf[1],
                  0.f, nullptr, nullptr, tid, lane, wave);
    barrier_lds();
    // P4: t2 || wb_x2 -> hbuf[0]
    gemm_phase<1>(Wp + 4 * 65536, Wp + 2 * 65536, hbuf[1], tacc, afr,
                  xacc, &params[5 * 256], hbuf[0],
                  0.f, nullptr, nullptr, tid, lane, wave);
    barrier_lds();
    // P5: x3 || wb_t2 -> hbuf[1]
    gemm_phase<1>(Wp + 2 * 65536, Wp + 5 * 65536, hbuf[0], xacc, afr,
                  tacc, &params[8 * 256], hbuf[1],
                  0.f, nullptr, nullptr, tid, lane, wave);
    barrier_lds();
    // P6: t3
    gemm_phase<0>(Wp + 5 * 65536, nullptr, hbuf[1], tacc, afr,
                  nullptr, nullptr, nullptr,
                  0.f, nullptr, nullptr, tid, lane, wave);

    // ----- combine: even/odd strided dot, fp32 -----
    // ch(reg,lane) = wave*64 + ci*32 + (reg&3) + 8*(reg>>2) + 4*kh;
    // parity = reg&1. row = ri*32 + ml.
    const float* xb3l = &params[6 * 256];
    const float* tb3l = &params[9 * 256];
    float ev[2] = {0.f, 0.f};
    float od[2] = {0.f, 0.f};
#pragma unroll
    for (int ci = 0; ci < 2; ++ci)
#pragma unroll
        for (int gq = 0; gq < 4; ++gq) {
            int nb = wave * 64 + ci * 32 + gq * 8 + 4 * kh;
            f32x4 xb = *(const f32x4*)&xb3l[nb];
            f32x4 tb = *(const f32x4*)&tb3l[nb];
#pragma unroll
            for (int ri = 0; ri < 2; ++ri) {
                float a0 = xacc[ci][ri][gq * 4 + 0] + xb[0], c0 = tacc[ci][ri][gq * 4 + 0] + tb[0];
                float a1 = xacc[ci][ri][gq * 4 + 1] + xb[1], c1 = tacc[ci][ri][gq * 4 + 1] + tb[1];
                float a2 = xacc[ci][ri][gq * 4 + 2] + xb[2], c2 = tacc[ci][ri][gq * 4 + 2] + tb[2];
                float a3 = xacc[ci][ri][gq * 4 + 3] + xb[3], c3 = tacc[ci][ri][gq * 4 + 3] + tb[3];
                ev[ri] += a0 * c0 + a2 * c2;
                od[ri] += a1 * c1 + a3 * c3;
            }
        }
#pragma unroll
    for (int ri = 0; ri < 2; ++ri) {         // partner lane+32: same row, other ch half
        ev[ri] += __shfl_xor(ev[ri], 32, 64);
        od[ri] += __shfl_xor(od[ri], 32, 64);
    }

    // hbuf[0] dead: its last readers (P5) all passed the P5->P6 barrier.
    float* red = (float*)hbuf[0];
    if (lane < 32) {
#pragma unroll
        for (int ri = 0; ri < 2; ++ri) {
            red[wave * 128 + ri * 64 + ml * 2 + 0] = ev[ri];
            red[wave * 128 + ri * 64 + ml * 2 + 1] = od[ri];
        }
    }
    __syncthreads();
    if (tid < 128) {                         // sum the 4 wave partials; coalesced store
        int p = tid & 1, row = tid >> 1;     // row 0..63
        int base = (row >> 5) * 64 + (row & 31) * 2 + p;
        float s = red[base] + red[128 + base] + red[256 + base] + red[384 + base];
        out[(row0 + row) * 2 + p] = s;
    }
}

// ---------------------------------------------------------------------------
extern "C" void kernel_launch(void* const* d_in, const int* in_sizes, int n_in,
                              void* d_out, int out_size, void* d_ws, size_t ws_size,
                              hipStream_t stream)
{
    const float* x   = (const float*)d_in[0];
    const float* xW0 = (const float*)d_in[1];
    const float* xb0 = (const float*)d_in[2];
    const float* xW1 = (const float*)d_in[3];
    const float* xb1 = (const float*)d_in[4];
    const float* xW2 = (const float*)d_in[5];
    const float* xb2 = (const float*)d_in[6];
    const float* xW3 = (const float*)d_in[7];
    const float* xb3 = (const float*)d_in[8];
    const float* tW0 = (const float*)d_in[9];
    const float* tb0 = (const float*)d_in[10];
    const float* tW1 = (const float*)d_in[11];
    const float* tb1 = (const float*)d_in[12];
    const float* tW2 = (const float*)d_in[13];
    const float* tb2 = (const float*)d_in[14];
    const float* tW3 = (const float*)d_in[15];
    const float* tb3 = (const float*)d_in[16];

    _Float16* Wp = (_Float16*)d_ws;          // 6*65536 fp16 = 768 KB
    const int N = in_sizes[0] / 2;           // 1,000,000 (divisible by 64)

    prepack<<<1536, 256, 0, stream>>>(xW1, xW2, xW3, tW1, tW2, tW3, Wp);
    mlp_fused<<<N / 64, 256, 0, stream>>>(x, xW0, xb0, xb1, xb2, xb3,
                                          tW0, tb0, tb1, tb2, tb3,
                                          Wp, (float*)d_out);
}

// Round 14
// 864.973 us; speedup vs baseline: 1.1049x; 1.1049x over previous
//
#include <hip/hip_runtime.h>

// SP_DNN: two fused 1->256->256->256->256 MLPs (sin activations) + strided rowwise dot.
// fp16 MFMA (16x16x32), fp32 accumulate.
//
// R14: halve the A-weight L2 traffic. R13 budget analysis: per CU phase-period,
// MFMA needs ~4966 cyc and the A-stream (256 KB @ ~56 B/cyc L2) ~4681; measured
// ~9814 = the SUM -> the kernel is L2-BW-bound on weights (12 GB total) and
// serialized. Traffic, not latency, is the wall -> bigger row tile:
//   block = 512 threads (8 waves), 128 rows; wave owns 32 ch x 128 rows
//   (channel-split: NO A duplication, unlike R3's row-split). A-bytes/MAC
//   halves -> 6 GB total (~200us L2 < 379us MFMA). LDS 2x64KB acts + 10KB
//   params = 138 KB -> 1 block/CU, still 2 waves/SIMD.
// Kept from R10/R11 (808us best): 6 alternating x/t phases, other-MLP wb +
// layer0_t sliced into the MFMA shadow, depth-2 A register pipeline chaining
// across phases, lgkm-only raw barriers, params in LDS, hswz swizzle.
// B single-buffered (bfr[8], reload-after-last-use) to keep regs ~215<=256.
// N=1e6 not divisible by 128: last block guards x-load / out-store.

typedef _Float16 f16x8 __attribute__((ext_vector_type(8)));
typedef _Float16 f16x4 __attribute__((ext_vector_type(4)));
typedef float f32x4 __attribute__((ext_vector_type(4)));

// Swizzled act-buffer byte offset: row m (0..127, 512 B stride), kbyte in
// [0,512). 16B unit index XORed with (m&7): any 8-lane chunk of a B-read
// covers all 32 banks exactly once; writeback/layer0 patterns are <=2-way.
__device__ __forceinline__ int hswz(int m, int kbyte) {
    return m * 512 + ((((kbyte >> 4) ^ (m & 7)) & 31) << 4) + (kbyte & 15);
}

// Raw workgroup barrier draining LDS ops only; global loads stay in flight.
__device__ __forceinline__ void barrier_lds() {
    asm volatile("s_waitcnt lgkmcnt(0)" ::: "memory");
    __builtin_amdgcn_s_barrier();
}

// ---------------------------------------------------------------------------
// Prepack: 6 matrices W[k][n] (256x256 f32, k-major) -> fp16 A-fragment-major
// for the 8-wave geometry:
//   idx = g*8192 + w*1024 + ci*512 + l*8 + j     (l = lane 0..63)
//   n = w*32 + ci*16 + (l&15),  k = g*32 + (l>>4)*8 + j
// Field map: j bits0-2, l bits3-8, ci bit9, w bits10-12, g bits13-15.
// ---------------------------------------------------------------------------
__global__ void prepack(const float* __restrict__ xW1, const float* __restrict__ xW2,
                        const float* __restrict__ xW3, const float* __restrict__ tW1,
                        const float* __restrict__ tW2, const float* __restrict__ tW3,
                        _Float16* __restrict__ dst)
{
    int g = blockIdx.x * 256 + threadIdx.x;   // 6*65536 threads exactly
    int L = g >> 16;
    int r = g & 65535;
    int j  = r & 7;            // bits 0-2
    int l  = (r >> 3) & 63;    // bits 3-8
    int ci = (r >> 9) & 1;     // bit 9
    int w  = (r >> 10) & 7;    // bits 10-12
    int gg = (r >> 13) & 7;    // bits 13-15
    const float* W;
    switch (L) {
        case 0: W = xW1; break;
        case 1: W = xW2; break;
        case 2: W = xW3; break;
        case 3: W = tW1; break;
        case 4: W = tW2; break;
        default: W = tW3; break;
    }
    int n = w * 32 + ci * 16 + (l & 15);
    int k = gg * 32 + ((l >> 4) & 3) * 8 + j;
    dst[g] = (_Float16)W[k * 256 + n];
}

// ---------------------------------------------------------------------------
// Main fused kernel. Block = 512 threads (8 waves), tile = 128 rows.
// Wave w owns out-channels [w*32, w*32+32) for all 128 rows.
// acc[ci][ri]: ci = ch frag (2 x 16ch), ri = row frag (8 x 16 rows).
// ---------------------------------------------------------------------------

__device__ __forceinline__ void layer0_scalar(
    float xv, const float* __restrict__ W0, const float* __restrict__ b0,
    _Float16* __restrict__ hb, int tid)
{
    int m = tid >> 2;        // 128 rows, 4 threads per row
    int q = tid & 3;
#pragma unroll
    for (int g = 0; g < 8; ++g) {
        int n0 = g * 32 + q * 8;        // 4 q-addresses -> 4 distinct banks
        f16x8 hv;
#pragma unroll
        for (int e = 0; e < 8; ++e) {
            float z = fmaf(xv, W0[n0 + e], b0[n0 + e]);
            hv[e] = (_Float16)__sinf(z);
        }
        *(f16x8*)((char*)hb + hswz(m, n0 * 2)) = hv;
    }
}

// One GEMM phase: acc = Wl x rb (8 K-groups, 16 MFMA each: 2 ch x 8 row frags).
// A: afr[2][2] depth-2 register pipeline (refill buf[g&1] for g+2 after last
//    use; g=6/7 load Wnext's g0/g1 -- in flight across the caller's barrier).
// B: bfr[8] single-buffered; reload for g+1 right after the cluster (WAR-safe).
// MODE 1: slice the OTHER MLP's writeback sin(wacc+bias[LDS]) -> wb_lds,
//         2 of 16 frags per g (s=2g+jo: ci=s>>3, ri=s&7).
// MODE 2: slice layer0_t, one 8-channel group per g (all 128 rows).
template<int MODE>   // 0 plain, 1 writeback, 2 layer0-slice
__device__ __forceinline__ void gemm_phase(
    const _Float16* __restrict__ Wl,
    const _Float16* __restrict__ Wnext,    // nullptr at the end
    const _Float16* __restrict__ rb,       // LDS read buffer (activations)
    f32x4 acc[2][8], f16x8 afr[2][2],
    f32x4 wacc[2][8],                      // MODE 1: prev phase's acc
    const float* __restrict__ wbias,       // MODE 1: LDS bias for wacc
    _Float16* __restrict__ wb_lds,         // MODE 1/2: LDS write target
    float xv,                              // MODE 2: scalar input
    const float* __restrict__ W0,          // MODE 2: LDS 1->256 weights
    const float* __restrict__ b0,          // MODE 2: LDS bias
    int tid, int lane, int ln, int quad, int wave)
{
    f32x4 zero = {0.f, 0.f, 0.f, 0.f};
#pragma unroll
    for (int ci = 0; ci < 2; ++ci)
#pragma unroll
        for (int ri = 0; ri < 8; ++ri)
            acc[ci][ri] = zero;

    const _Float16* abase = Wl + wave * 1024 + lane * 8;

    // B prologue: g0 (8 ds_read_b128).
    f16x8 bfr[8];
#pragma unroll
    for (int ri = 0; ri < 8; ++ri)
        bfr[ri] = *(const f16x8*)((const char*)rb +
                                  hswz(16 * ri + ln, quad * 16));

#pragma unroll
    for (int g = 0; g < 8; ++g) {
        __builtin_amdgcn_s_setprio(1);
#pragma unroll
        for (int ci = 0; ci < 2; ++ci)
#pragma unroll
            for (int ri = 0; ri < 8; ++ri)
                acc[ci][ri] = __builtin_amdgcn_mfma_f32_16x16x32_f16(
                    afr[g & 1][ci], bfr[ri], acc[ci][ri], 0, 0, 0);
        __builtin_amdgcn_s_setprio(0);

        // B reload for g+1 (program-order after the cluster's last use).
        if (g < 7) {
#pragma unroll
            for (int ri = 0; ri < 8; ++ri)
                bfr[ri] = *(const f16x8*)((const char*)rb +
                              hswz(16 * ri + ln, (g + 1) * 64 + quad * 16));
        }
        // A refill buf[g&1] for g+2; g=6/7 chain to the NEXT phase's g0/g1.
        if (g < 6) {
#pragma unroll
            for (int ci = 0; ci < 2; ++ci)
                afr[g & 1][ci] = *(const f16x8*)(abase + (g + 2) * 8192 + ci * 512);
        } else if (Wnext) {
#pragma unroll
            for (int ci = 0; ci < 2; ++ci)
                afr[g & 1][ci] = *(const f16x8*)(Wnext + (g - 6) * 8192 +
                                                 wave * 1024 + lane * 8 + ci * 512);
        }

        if (MODE == 1) {                 // writeback slice: 2 of 16 frags
#pragma unroll
            for (int jo = 0; jo < 2; ++jo) {
                const int s  = g * 2 + jo;
                const int cw = s >> 3, rw = s & 7;
                const int nb = wave * 32 + cw * 16 + quad * 4;
                f32x4 bv = *(const f32x4*)&wbias[nb];
                f16x4 hv;
                hv[0] = (_Float16)__sinf(wacc[cw][rw][0] + bv[0]);
                hv[1] = (_Float16)__sinf(wacc[cw][rw][1] + bv[1]);
                hv[2] = (_Float16)__sinf(wacc[cw][rw][2] + bv[2]);
                hv[3] = (_Float16)__sinf(wacc[cw][rw][3] + bv[3]);
                *(f16x4*)((char*)wb_lds + hswz(16 * rw + ln, nb * 2)) = hv;
            }
        } else if (MODE == 2) {          // layer0 slice: one 8-ch group
            const int m = tid >> 2, q = tid & 3;
            const int n0 = g * 32 + q * 8;
            f16x8 hv;
#pragma unroll
            for (int e = 0; e < 8; ++e) {
                float z = fmaf(xv, W0[n0 + e], b0[n0 + e]);
                hv[e] = (_Float16)__sinf(z);
            }
            *(f16x8*)((char*)wb_lds + hswz(m, n0 * 2)) = hv;
        }
    }
}

__global__ __launch_bounds__(512, 2)
void mlp_fused(const float* __restrict__ x,
               const float* __restrict__ xW0, const float* __restrict__ xb0,
               const float* __restrict__ xb1, const float* __restrict__ xb2,
               const float* __restrict__ xb3,
               const float* __restrict__ tW0, const float* __restrict__ tb0,
               const float* __restrict__ tb1, const float* __restrict__ tb2,
               const float* __restrict__ tb3,
               const _Float16* __restrict__ Wp,
               float* __restrict__ out, int N)
{
    __shared__ __align__(16) _Float16 hbuf[2][128 * 256];  // 2 x 64 KB acts
    __shared__ __align__(16) float    params[10 * 256];    // 10 KB small params

    const int tid = threadIdx.x;
    const int lane = tid & 63;
    const int wave = tid >> 6;       // 0..7
    const int ln = lane & 15;
    const int quad = lane >> 4;
    const int row0 = blockIdx.x * 128;

    // Preload all small params to LDS (512 threads: first 256 entries each of
    // 10 segs done by tid<256; use both halves for 5+5).
    // segs: 0 xW0, 1 xb0, 2 tW0, 3 tb0, 4 xb1, 5 xb2, 6 xb3, 7 tb1, 8 tb2, 9 tb3
    {
        const float* psrc[10] = {xW0, xb0, tW0, tb0, xb1, xb2, xb3, tb1, tb2, tb3};
        int half = tid >> 8, e = tid & 255;      // half 0: segs 0-4, half 1: 5-9
#pragma unroll
        for (int s = 0; s < 5; ++s)
            params[(half * 5 + s) * 256 + e] = psrc[half * 5 + s][e];
    }
    const int myrow = row0 + (tid >> 2);
    const float2 xv2 = (myrow < N) ? ((const float2*)x)[myrow]
                                   : make_float2(0.f, 0.f);

    f32x4 xacc[2][8], tacc[2][8];    // 128 AGPR
    f16x8 afr[2][2];                 // A-fragment register double-buffer (16 VGPR)

    // Prologue: xW1 g0 -> buf0, g1 -> buf1; land during layer0_x's sin work.
#pragma unroll
    for (int s = 0; s < 2; ++s)
#pragma unroll
        for (int ci = 0; ci < 2; ++ci)
            afr[s][ci] = *(const f16x8*)(Wp + s * 8192 + wave * 1024 +
                                         lane * 8 + ci * 512);
    barrier_lds();                    // params visible to all waves

    // ----- layer0_x -----
    layer0_scalar(xv2.x, &params[0], &params[256], hbuf[0], tid);
    barrier_lds();                    // x acts visible

    // ----- 6 alternating GEMM phases -----
    // P1: x1; layer0_t sliced in -> hbuf[1]
    gemm_phase<2>(Wp + 0 * 65536, Wp + 3 * 65536, hbuf[0], xacc, afr,
                  nullptr, nullptr, hbuf[1],
                  xv2.y, &params[2 * 256], &params[3 * 256],
                  tid, lane, ln, quad, wave);
    barrier_lds();
    // P2: t1 || wb_x1 -> hbuf[0]
    gemm_phase<1>(Wp + 3 * 65536, Wp + 1 * 65536, hbuf[1], tacc, afr,
                  xacc, &params[4 * 256], hbuf[0],
                  0.f, nullptr, nullptr, tid, lane, ln, quad, wave);
    barrier_lds();
    // P3: x2 || wb_t1 -> hbuf[1]
    gemm_phase<1>(Wp + 1 * 65536, Wp + 4 * 65536, hbuf[0], xacc, afr,
                  tacc, &params[7 * 256], hbuf[1],
                  0.f, nullptr, nullptr, tid, lane, ln, quad, wave);
    barrier_lds();
    // P4: t2 || wb_x2 -> hbuf[0]
    gemm_phase<1>(Wp + 4 * 65536, Wp + 2 * 65536, hbuf[1], tacc, afr,
                  xacc, &params[5 * 256], hbuf[0],
                  0.f, nullptr, nullptr, tid, lane, ln, quad, wave);
    barrier_lds();
    // P5: x3 || wb_t2 -> hbuf[1]
    gemm_phase<1>(Wp + 2 * 65536, Wp + 5 * 65536, hbuf[0], xacc, afr,
                  tacc, &params[8 * 256], hbuf[1],
                  0.f, nullptr, nullptr, tid, lane, ln, quad, wave);
    barrier_lds();
    // P6: t3
    gemm_phase<0>(Wp + 5 * 65536, nullptr, hbuf[1], tacc, afr,
                  nullptr, nullptr, nullptr,
                  0.f, nullptr, nullptr, tid, lane, ln, quad, wave);

    // ----- combine: even/odd strided dot, fp32 -----
    // channel = wave*32 + ci*16 + quad*4 + r (parity = r&1); row = 16*ri+ln.
    const float* xb3l = &params[6 * 256];
    const float* tb3l = &params[9 * 256];
    float ev[8], od[8];
#pragma unroll
    for (int ri = 0; ri < 8; ++ri) { ev[ri] = 0.f; od[ri] = 0.f; }
#pragma unroll
    for (int ci = 0; ci < 2; ++ci) {
        int nb = wave * 32 + ci * 16 + quad * 4;
        f32x4 xb = *(const f32x4*)&xb3l[nb];
        f32x4 tb = *(const f32x4*)&tb3l[nb];
#pragma unroll
        for (int ri = 0; ri < 8; ++ri) {
            float a0 = xacc[ci][ri][0] + xb[0], c0 = tacc[ci][ri][0] + tb[0];
            float a1 = xacc[ci][ri][1] + xb[1], c1 = tacc[ci][ri][1] + tb[1];
            float a2 = xacc[ci][ri][2] + xb[2], c2 = tacc[ci][ri][2] + tb[2];
            float a3 = xacc[ci][ri][3] + xb[3], c3 = tacc[ci][ri][3] + tb[3];
            ev[ri] += a0 * c0 + a2 * c2;     // channel parity = reg index parity
            od[ri] += a1 * c1 + a3 * c3;
        }
    }
#pragma unroll
    for (int ri = 0; ri < 8; ++ri) {         // reduce over the 4 quads
        ev[ri] += __shfl_xor(ev[ri], 16, 64);
        ev[ri] += __shfl_xor(ev[ri], 32, 64);
        od[ri] += __shfl_xor(od[ri], 16, 64);
        od[ri] += __shfl_xor(od[ri], 32, 64);
    }

    // hbuf[0] dead: its last readers (P5) all passed the P5->P6 barrier.
    // Per-wave partials: 8 waves x (8 ri x 16 ln x 2 parities) = 8 KB.
    float* red = (float*)hbuf[0];
    if (lane < 16) {
#pragma unroll
        for (int ri = 0; ri < 8; ++ri) {
            red[wave * 256 + ri * 32 + ln * 2 + 0] = ev[ri];
            red[wave * 256 + ri * 32 + ln * 2 + 1] = od[ri];
        }
    }
    __syncthreads();
    if (tid < 256) {                         // 1 thread per (row, parity)
        int p = tid & 1, row = tid >> 1;     // row 0..127
        int base = (row >> 4) * 32 + (row & 15) * 2 + p;
        float s = 0.f;
#pragma unroll
        for (int w = 0; w < 8; ++w)          // sum the 8 wave partials
            s += red[w * 256 + base];
        if (row0 + row < N)
            out[(row0 + row) * 2 + p] = s;
    }
}

// ---------------------------------------------------------------------------
extern "C" void kernel_launch(void* const* d_in, const int* in_sizes, int n_in,
                              void* d_out, int out_size, void* d_ws, size_t ws_size,
                              hipStream_t stream)
{
    const float* x   = (const float*)d_in[0];
    const float* xW0 = (const float*)d_in[1];
    const float* xb0 = (const float*)d_in[2];
    const float* xW1 = (const float*)d_in[3];
    const float* xb1 = (const float*)d_in[4];
    const float* xW2 = (const float*)d_in[5];
    const float* xb2 = (const float*)d_in[6];
    const float* xW3 = (const float*)d_in[7];
    const float* xb3 = (const float*)d_in[8];
    const float* tW0 = (const float*)d_in[9];
    const float* tb0 = (const float*)d_in[10];
    const float* tW1 = (const float*)d_in[11];
    const float* tb1 = (const float*)d_in[12];
    const float* tW2 = (const float*)d_in[13];
    const float* tb2 = (const float*)d_in[14];
    const float* tW3 = (const float*)d_in[15];
    const float* tb3 = (const float*)d_in[16];

    _Float16* Wp = (_Float16*)d_ws;          // 6*65536 fp16 = 768 KB
    const int N = in_sizes[0] / 2;           // 1,000,000
    const int nblk = (N + 127) / 128;        // 7813 (last block: 64 valid rows)

    prepack<<<1536, 256, 0, stream>>>(xW1, xW2, xW3, tW1, tW2, tW3, Wp);
    mlp_fused<<<nblk, 512, 0, stream>>>(x, xW0, xb0, xb1, xb2, xb3,
                                        tW0, tb0, tb1, tb2, tb3,
                                        Wp, (float*)d_out, N);
}